// Round 4
// baseline (925.780 us; speedup 1.0000x reference)
//
#include <hip/hip_runtime.h>

#define NROWS (128*8192)
#define D 128
#define HID 128
#define NBAGS 128
#define BAG 8192

typedef __bf16 bf16x8 __attribute__((ext_vector_type(8)));
typedef float  f32x16 __attribute__((ext_vector_type(16)));

__device__ inline float tanh_fast(float v){
  float a = fabsf(v);
  float e = __expf(2.0f * a);          // e^{2a}; overflow -> inf -> r=1, safe
  float r = 1.0f - 2.0f / (e + 1.0f);
  return copysignf(r, v);
}

// ---------------------------------------------------------------------------
// K1: logits[i] = tanh(x[i]·W1 + b1)·W2 + b2  via bf16x3-split MFMA.
// One wave = 32 rows. W1 staged in LDS as swizzled bf16 hi/lo fragments.
// A-frag (32x32x16): lane l holds x[row = l&31][k = (l>>5)*8 + j], j=0..7
// B-frag:            lane l holds W1[k = (l>>5)*8 + j][col = l&31]
// C/D (HW-verified): lane l, reg q -> row=(q&3)+8*(q>>2)+4*(l>>5), col=l&31
// LDS = 64 KB exactly (2 blocks/CU).
// ---------------------------------------------------------------------------
__global__ __launch_bounds__(256) void k_logits(
    const float* __restrict__ x, const float* __restrict__ W1,
    const float* __restrict__ b1, const float* __restrict__ W2,
    const float* __restrict__ b2, float* __restrict__ logits)
{
  __shared__ __bf16 Bh[16384];   // [t(4)][kk(8)][lane(64)][j(8)]
  __shared__ __bf16 Bl[16384];
  const int tid = threadIdx.x;

  // Stage W1 -> swizzled bf16 hi/lo fragments (once per persistent block)
  for (int idx = tid; idx < 16384; idx += 256){
    int j  = idx & 7;
    int l  = (idx >> 3) & 63;
    int kk = (idx >> 9) & 7;
    int t  = idx >> 12;
    int k  = kk*16 + ((l >> 5) << 3) + j;
    int c  = t*32 + (l & 31);
    float v = W1[k*HID + c];
    __bf16 h = (__bf16)v;                 // RNE hardware cvt
    Bh[idx] = h;
    Bl[idx] = (__bf16)(v - (float)h);
  }
  __syncthreads();

  const int lane  = tid & 63;
  const int wave  = tid >> 6;
  const int gwave = blockIdx.x * 4 + wave;
  const int nwv   = gridDim.x * 4;

  float w2v[4], b1v[4];
  #pragma unroll
  for (int t = 0; t < 4; ++t){
    w2v[t] = W2[t*32 + (lane & 31)];
    b1v[t] = b1[t*32 + (lane & 31)];
  }
  const float b2v = b2[0];

  const int rowl = lane & 31;
  const int kgrp = lane >> 5;   // 0/1

  for (int tile = gwave; tile < NROWS/32; tile += nwv){
    const float* xr = x + (size_t)(tile*32 + rowl) * D + kgrp*8;

    // prefetch this lane's 8 f32 per K-chunk (covers 32 rows x 128 k/wave)
    float4 u0[8], u1[8];
    #pragma unroll
    for (int kk = 0; kk < 8; ++kk){
      u0[kk] = *(const float4*)(xr + kk*16);
      u1[kk] = *(const float4*)(xr + kk*16 + 4);
    }

    f32x16 acc[4];
    #pragma unroll
    for (int t = 0; t < 4; ++t) acc[t] = (f32x16)(0.0f);

    #pragma unroll
    for (int kk = 0; kk < 8; ++kk){
      float f[8] = {u0[kk].x, u0[kk].y, u0[kk].z, u0[kk].w,
                    u1[kk].x, u1[kk].y, u1[kk].z, u1[kk].w};
      bf16x8 ah, al;
      #pragma unroll
      for (int j = 0; j < 8; ++j){
        __bf16 h = (__bf16)f[j];          // hardware v_cvt (RNE)
        ah[j] = h;
        al[j] = (__bf16)(f[j] - (float)h);
      }
      #pragma unroll
      for (int t = 0; t < 4; ++t){
        int base = ((t*8 + kk)*64 + lane)*8;
        bf16x8 bh = *reinterpret_cast<const bf16x8*>(&Bh[base]);
        bf16x8 bl = *reinterpret_cast<const bf16x8*>(&Bl[base]);
        acc[t] = __builtin_amdgcn_mfma_f32_32x32x16_bf16(ah, bh, acc[t], 0, 0, 0);
        acc[t] = __builtin_amdgcn_mfma_f32_32x32x16_bf16(ah, bl, acc[t], 0, 0, 0);
        acc[t] = __builtin_amdgcn_mfma_f32_32x32x16_bf16(al, bh, acc[t], 0, 0, 0);
      }
    }

    // epilogue: logit[row] = sum_col tanh(h + b1[col])*W2[col]; 32-lane reduce
    float p[16];
    #pragma unroll
    for (int q = 0; q < 16; ++q) p[q] = 0.0f;
    #pragma unroll
    for (int t = 0; t < 4; ++t){
      #pragma unroll
      for (int q = 0; q < 16; ++q){
        p[q] += tanh_fast(acc[t][q] + b1v[t]) * w2v[t];
      }
    }
    #pragma unroll
    for (int m = 1; m < 32; m <<= 1){
      #pragma unroll
      for (int q = 0; q < 16; ++q) p[q] += __shfl_xor(p[q], m);
    }
    if ((lane & 31) == 0){
      int rb = tile*32 + (kgrp << 2);
      #pragma unroll
      for (int q = 0; q < 16; ++q){
        int row = (q & 3) + 8*(q >> 2);
        logits[rb + row] = p[q] + b2v;     // TEMP == 1.0
      }
    }
  }
}

// ---------------------------------------------------------------------------
// K2: per-bag softmax + tridiagonal smooth + renorm, in place (logits -> g).
// One block per bag; whole bag (32 KB) staged in LDS. LDS = 64 KB exactly;
// reductions reuse dead regions of lb/wb (no separate scratch).
// ---------------------------------------------------------------------------
__global__ __launch_bounds__(256) void k_soft(float* __restrict__ g)
{
  __shared__ float lb[BAG];   // logits, later g_raw
  __shared__ float wb[BAG];   // e, later w
  const int tid = threadIdx.x;
  float* seg = g + (size_t)blockIdx.x * BAG;

  float4* lb4 = (float4*)lb;
  const float4* s4 = (const float4*)seg;
  #pragma unroll
  for (int i = 0; i < 8; ++i) lb4[i*256 + tid] = s4[i*256 + tid];
  __syncthreads();

  // ---- max (scratch: wb[0..255], not yet holding e) ----
  float m = -3.4e38f;
  #pragma unroll
  for (int i = 0; i < 32; ++i) m = fmaxf(m, lb[i*256 + tid]);
  wb[tid] = m; __syncthreads();
  for (int s = 128; s > 0; s >>= 1){
    if (tid < s) wb[tid] = fmaxf(wb[tid], wb[tid+s]);
    __syncthreads();
  }
  m = wb[0]; __syncthreads();

  // ---- e = exp(l-m); sum (scratch: lb[0..255], logits consumed) ----
  // per-thread slots i*256+tid are disjoint across threads; lb[tid] is only
  // re-read by thread tid itself, after its own loop -> no barrier needed.
  float ls = 0.0f;
  #pragma unroll
  for (int i = 0; i < 32; ++i){
    float e = __expf(lb[i*256 + tid] - m);
    wb[i*256 + tid] = e;
    ls += e;
  }
  lb[tid] = ls; __syncthreads();
  for (int s = 128; s > 0; s >>= 1){
    if (tid < s) lb[tid] += lb[tid+s];
    __syncthreads();
  }
  float s_sum = lb[0]; __syncthreads();

  // ---- w = e / s ----
  #pragma unroll
  for (int i = 0; i < 32; ++i) wb[i*256 + tid] = wb[i*256 + tid] / s_sum;
  __syncthreads();

  // ---- smooth: g = 0.5 w + 0.5 (w + wl + wr)/deg  (reads wb, writes lb) ----
  float gs = 0.0f;
  #pragma unroll
  for (int i = 0; i < 32; ++i){
    int idx = i*256 + tid;
    float w  = wb[idx];
    float wl = (idx > 0)       ? wb[idx-1] : 0.0f;
    float wr = (idx < BAG-1)   ? wb[idx+1] : 0.0f;
    float deg = 1.0f + (idx > 0 ? 1.0f : 0.0f) + (idx < BAG-1 ? 1.0f : 0.0f);
    float gg = 0.5f*w + 0.5f*(w + wl + wr)/deg;
    lb[idx] = gg;
    gs += gg;
  }
  __syncthreads();              // neighbors' wb reads must finish first
  // ---- g-sum (scratch: wb[0..255], w consumed) ----
  wb[tid] = gs; __syncthreads();
  for (int s = 128; s > 0; s >>= 1){
    if (tid < s) wb[tid] += wb[tid+s];
    __syncthreads();
  }
  float denom = wb[0] + 1e-8f;

  #pragma unroll
  for (int i = 0; i < 32; ++i){
    int idx = i*256 + tid;
    seg[idx] = lb[idx] / denom;   // each thread reads only its own writes
  }
}

// ---------------------------------------------------------------------------
// K3: ctx[bag] = sum g[i]*x[i].  8 blocks per bag, atomicAdd partials.
// tid = rg(8 rows) x fq(32 feat-quads); fully coalesced float4 reads of x.
// ---------------------------------------------------------------------------
__global__ __launch_bounds__(256) void k_ctx(
    const float* __restrict__ x, const float* __restrict__ g,
    float* __restrict__ ctx)
{
  __shared__ float4 red4[256];
  const int tid = threadIdx.x;
  const int fq  = tid & 31;
  const int rg  = tid >> 5;
  const int blk = blockIdx.x;
  const int bag = blk >> 3;
  const int r0  = bag*BAG + (blk & 7)*1024;
  const float4* x4 = (const float4*)x;

  float4 acc; acc.x = acc.y = acc.z = acc.w = 0.0f;
  #pragma unroll 8
  for (int it = 0; it < 128; ++it){
    int r = r0 + it*8 + rg;
    float gv = g[r];
    float4 xv = x4[(size_t)r*32 + fq];
    acc.x += gv*xv.x; acc.y += gv*xv.y; acc.z += gv*xv.z; acc.w += gv*xv.w;
  }
  red4[tid] = acc; __syncthreads();
  for (int s = 128; s >= 32; s >>= 1){
    if (tid < s){
      red4[tid].x += red4[tid+s].x;
      red4[tid].y += red4[tid+s].y;
      red4[tid].z += red4[tid+s].z;
      red4[tid].w += red4[tid+s].w;
    }
    __syncthreads();
  }
  if (tid < 32){
    float4 v = red4[tid];
    float* dst = ctx + bag*128 + fq*4;
    atomicAdd(dst + 0, v.x);
    atomicAdd(dst + 1, v.y);
    atomicAdd(dst + 2, v.z);
    atomicAdd(dst + 3, v.w);
  }
}

extern "C" void kernel_launch(void* const* d_in, const int* in_sizes, int n_in,
                              void* d_out, int out_size, void* d_ws, size_t ws_size,
                              hipStream_t stream)
{
  const float* x  = (const float*)d_in[0];
  const float* W1 = (const float*)d_in[1];
  const float* b1 = (const float*)d_in[2];
  const float* W2 = (const float*)d_in[3];
  const float* b2 = (const float*)d_in[4];
  // d_in[5] = lengths (int32, all == 8192) — bags contiguous, fixed size.

  float* out = (float*)d_out;
  float* ctx = out;            // [128*128]
  float* g   = out + 16384;    // [N] — used first as logits scratch, then g

  hipMemsetAsync(ctx, 0, 16384*sizeof(float), stream);
  k_logits<<<512, 256, 0, stream>>>(x, W1, b1, W2, b2, g);
  k_soft  <<<NBAGS, 256, 0, stream>>>(g);
  k_ctx   <<<1024, 256, 0, stream>>>(x, g, ctx);
}